// Round 5
// baseline (82.508 us; speedup 1.0000x reference)
//
#include <hip/hip_runtime.h>
#include <math.h>

namespace {
constexpr int kB = 4, kT = 256, kS = 512, kH = 12, kD = 768, kV = 32000;
constexpr int HASH = 1024;   // 512 inserts, load factor 0.5
constexpr int NT = 512;      // 8 waves/block
constexpr int NW = NT / 64;

typedef float f32x4 __attribute__((ext_vector_type(4)));

// online-softmax accumulate of one f32x4 into (m, s)
__device__ __forceinline__ void acc4(float& m, float& s, f32x4 v) {
  float mx = fmaxf(fmaxf(v[0], v[1]), fmaxf(v[2], v[3]));
  if (mx > m) { s *= __expf(m - mx); m = mx; }
  s += __expf(v[0] - m) + __expf(v[1] - m) + __expf(v[2] - m) + __expf(v[3] - m);
}
__device__ __forceinline__ void merge2(float& ma, float& sa, float mb, float sb) {
  float mm = fmaxf(ma, mb);
  sa = sa * __expf(ma - mm) + sb * __expf(mb - mm);
  ma = mm;
}

__device__ __forceinline__ float wave_sum(float v) {
  #pragma unroll
  for (int off = 32; off > 0; off >>= 1) v += __shfl_down(v, off, 64);
  return v;
}
__device__ __forceinline__ float wave_max(float v) {
  #pragma unroll
  for (int off = 32; off > 0; off >>= 1) v = fmaxf(v, __shfl_down(v, off, 64));
  return v;
}

// ---------------- Kernel 1: per-row stats (p_gen, M, Z, base) ----------------
__global__ __launch_bounds__(NT) void k_stats(
    const float* __restrict__ dec_output,   // B,T,D
    const float* __restrict__ final_output, // B,T,V
    const float* __restrict__ W_pgen,       // D
    const float* __restrict__ b_pgen,       // 1
    f32x4* __restrict__ hdr)                // B*T x {pg, M, Z, base}
{
  const int bt   = blockIdx.x;
  const int tid  = threadIdx.x;
  const int lane = tid & 63;
  const int wid  = tid >> 6;

  __shared__ float redA[NW], redm[NW], reds[NW];

  // p_gen partial dot
  {
    const float* dec = dec_output + (size_t)bt * kD;
    float acc = dec[tid] * W_pgen[tid];
    if (tid < kD - NT) acc += dec[tid + NT] * W_pgen[tid + NT];
    acc = wave_sum(acc);
    if (lane == 0) redA[wid] = acc;
  }

  // online softmax over the 32000-wide row, 4 independent streams
  const f32x4* x4 = (const f32x4*)(final_output + (size_t)bt * kV);
  float m0 = -1e30f, s0 = 0.f, m1 = -1e30f, s1 = 0.f;
  float m2 = -1e30f, s2 = 0.f, m3 = -1e30f, s3 = 0.f;
  int f = tid;
  #pragma unroll
  for (int k = 0; k < 3; ++k) {              // covers [0, 6144)
    f32x4 a = x4[f], b = x4[f + NT], c = x4[f + 2 * NT], d = x4[f + 3 * NT];
    acc4(m0, s0, a); acc4(m1, s1, b); acc4(m2, s2, c); acc4(m3, s3, d);
    f += 4 * NT;
  }
  {                                           // covers [6144, 7680)
    f32x4 a = x4[f], b = x4[f + NT], c = x4[f + 2 * NT];
    acc4(m0, s0, a); acc4(m1, s1, b); acc4(m2, s2, c);
  }
  if (tid < (kV / 4 - 15 * NT)) {             // covers [7680, 8000)
    f32x4 a = x4[tid + 15 * NT];
    acc4(m3, s3, a);
  }
  merge2(m0, s0, m1, s1);
  merge2(m2, s2, m3, s3);
  merge2(m0, s0, m2, s2);

  // wave-level merge
  #pragma unroll
  for (int off = 32; off > 0; off >>= 1) {
    float mb = __shfl_down(m0, off, 64);
    float sb = __shfl_down(s0, off, 64);
    merge2(m0, s0, mb, sb);
  }
  if (lane == 0) { redm[wid] = m0; reds[wid] = s0; }
  __syncthreads();

  if (tid == 0) {
    float z = b_pgen[0];
    #pragma unroll
    for (int w = 0; w < NW; ++w) z += redA[w];
    float pg = 1.f / (1.f + expf(-z));
    float M = redm[0], Z = reds[0];
    #pragma unroll
    for (int w = 1; w < NW; ++w) merge2(M, Z, redm[w], reds[w]);
    f32x4 h;
    h[0] = pg; h[1] = M; h[2] = Z; h[3] = logf(pg) - M - logf(Z);
    hdr[bt] = h;
  }
}

// ---------------- Kernel 2: attention softmax + hash + emit + fixup ----------
__global__ __launch_bounds__(NT) void k_emit(
    const float* __restrict__ final_output, // B,T,V
    const float* __restrict__ attn_w,       // B,H,T,S
    const int*   __restrict__ enc,          // B,S
    const f32x4* __restrict__ hdr,          // B*T
    float* __restrict__ out)                // B,T,V
{
  const int bt   = blockIdx.x;
  const int b    = bt / kT;
  const int t    = bt - b * kT;
  const int tid  = threadIdx.x;
  const int lane = tid & 63;
  const int wid  = tid >> 6;

  __shared__ int   hkey[HASH];
  __shared__ float hval[HASH];
  __shared__ float redm[NW], reds[NW];

  for (int i = tid; i < HASH; i += NT) { hkey[i] = -1; hval[i] = 0.f; }

  f32x4 h = hdr[bt];
  const float pg = h[0], M = h[1], Z = h[2], base = h[3];

  // attention mean over heads + softmax over S (kS == NT: one s per thread)
  float val;
  {
    float a0 = 0.f;
    #pragma unroll
    for (int hh = 0; hh < kH; ++hh) {
      const float* ap = attn_w + (((size_t)b * kH + hh) * kT + t) * kS;
      a0 += ap[tid];
    }
    a0 *= (1.f / kH);
    float wm = wave_max(a0);
    if (lane == 0) redm[wid] = wm;
    __syncthreads();               // also publishes hash init
    float mx = redm[0];
    #pragma unroll
    for (int w = 1; w < NW; ++w) mx = fmaxf(mx, redm[w]);
    float e0 = __expf(a0 - mx);
    float ws = wave_sum(e0);
    if (lane == 0) reds[wid] = ws;
    __syncthreads();
    float tot = 0.f;
    #pragma unroll
    for (int w = 0; w < NW; ++w) tot += reds[w];
    val = e0 * ((1.f - pg) / tot);
  }

  // hash insert (token -> summed copy prob)
  {
    int key = enc[b * kS + tid];
    unsigned hpos = ((unsigned)key * 2654435761u) >> 22;
    while (true) {
      int prev = atomicCAS(&hkey[hpos], -1, key);
      if (prev == -1 || prev == key) { atomicAdd(&hval[hpos], val); break; }
      hpos = (hpos + 1) & (HASH - 1);
    }
  }

  // dense emit: out = x + base, 4-way unrolled streaming
  const f32x4* x4 = (const f32x4*)(final_output + (size_t)bt * kV);
  f32x4* o4 = (f32x4*)(out + (size_t)bt * kV);
  {
    int f = tid;
    #pragma unroll
    for (int k = 0; k < 3; ++k) {
      f32x4 a = x4[f], bb = x4[f + NT], c = x4[f + 2 * NT], d = x4[f + 3 * NT];
      __builtin_nontemporal_store(a + base, &o4[f]);
      __builtin_nontemporal_store(bb + base, &o4[f + NT]);
      __builtin_nontemporal_store(c + base, &o4[f + 2 * NT]);
      __builtin_nontemporal_store(d + base, &o4[f + 3 * NT]);
      f += 4 * NT;
    }
    {
      f32x4 a = x4[f], bb = x4[f + NT], c = x4[f + 2 * NT];
      __builtin_nontemporal_store(a + base, &o4[f]);
      __builtin_nontemporal_store(bb + base, &o4[f + NT]);
      __builtin_nontemporal_store(c + base, &o4[f + 2 * NT]);
    }
    if (tid < (kV / 4 - 15 * NT)) {
      f32x4 a = x4[tid + 15 * NT];
      __builtin_nontemporal_store(a + base, &o4[tid + 15 * NT]);
    }
  }
  __syncthreads();   // vmcnt drained -> fixup writes ordered after dense writes

  // fixup the <=512 copied tokens
  {
    const float* xrow = final_output + (size_t)bt * kV;
    float* orow = out + (size_t)bt * kV;
    float invZ = 1.f / Z;
    for (int i = tid; i < HASH; i += NT) {
      int key = hkey[i];
      if (key >= 0) {
        float c = hval[i];
        float x = xrow[key];
        orow[key] = logf(pg * expf(x - M) * invZ + c);
      }
    }
  }
}
}  // namespace

extern "C" void kernel_launch(void* const* d_in, const int* in_sizes, int n_in,
                              void* d_out, int out_size, void* d_ws, size_t ws_size,
                              hipStream_t stream) {
  const float* dec = (const float*)d_in[0];
  const float* fin = (const float*)d_in[1];
  const float* aw  = (const float*)d_in[2];
  const float* W   = (const float*)d_in[3];
  const float* bb  = (const float*)d_in[4];
  const int*   enc = (const int*)d_in[5];
  float* out = (float*)d_out;
  f32x4* hdr = (f32x4*)d_ws;   // 1024 * 16 B = 16 KB

  k_stats<<<dim3(kB * kT), dim3(NT), 0, stream>>>(dec, fin, W, bb, hdr);
  k_emit <<<dim3(kB * kT), dim3(NT), 0, stream>>>(fin, aw, enc, hdr, out);
}

// Round 6
// 60.939 us; speedup vs baseline: 1.3539x; 1.3539x over previous
//
#include <hip/hip_runtime.h>
#include <math.h>

namespace {
constexpr int kB = 4, kT = 256, kS = 512, kH = 12, kD = 768, kV = 32000;
constexpr int HASH = 1024;        // 512 inserts, load factor 0.5
constexpr int NT = 512;           // 8 waves/block
constexpr int NW = NT / 64;
constexpr int NF4 = kV / 4;       // 8000 f32x4 per row
constexpr int FULL = NF4 / NT;    // 15 full slices per thread
constexpr int REM = NF4 - FULL * NT;  // 320 threads hold one extra

typedef float f32x4 __attribute__((ext_vector_type(4)));

__device__ __forceinline__ void acc4(float& m, float& s, f32x4 v) {
  float mx = fmaxf(fmaxf(v[0], v[1]), fmaxf(v[2], v[3]));
  if (mx > m) { s *= __expf(m - mx); m = mx; }
  s += __expf(v[0] - m) + __expf(v[1] - m) + __expf(v[2] - m) + __expf(v[3] - m);
}
__device__ __forceinline__ void merge2(float& ma, float& sa, float mb, float sb) {
  float mm = fmaxf(ma, mb);
  sa = sa * __expf(ma - mm) + sb * __expf(mb - mm);
  ma = mm;
}
__device__ __forceinline__ float wave_sum(float v) {
  #pragma unroll
  for (int off = 32; off > 0; off >>= 1) v += __shfl_down(v, off, 64);
  return v;
}
__device__ __forceinline__ float wave_max(float v) {
  #pragma unroll
  for (int off = 32; off > 0; off >>= 1) v = fmaxf(v, __shfl_down(v, off, 64));
  return v;
}

// One fused kernel, row register-resident: read final_output exactly once.
__global__ __launch_bounds__(NT, 4) void pg_fused(
    const float* __restrict__ dec_output,   // B,T,D
    const float* __restrict__ final_output, // B,T,V
    const float* __restrict__ attn_w,       // B,H,T,S
    const float* __restrict__ W_pgen,       // D
    const float* __restrict__ b_pgen,       // 1
    const int*   __restrict__ enc,          // B,S
    float* __restrict__ out)                // B,T,V
{
  const int bt   = blockIdx.x;
  const int b    = bt / kT;
  const int t    = bt - b * kT;
  const int tid  = threadIdx.x;
  const int lane = tid & 63;
  const int wid  = tid >> 6;

  __shared__ int   hkey[HASH];
  __shared__ float hval[HASH];
  __shared__ float redA[NW];                 // p_gen partials
  __shared__ float redm[NW], reds[NW];       // attn softmax
  __shared__ float redm2[NW], reds2[NW];     // row softmax (separate: no WAR race)

  // ---- issue small loads first (dec, attn, enc), then the row burst ----
  const float* dec = dec_output + (size_t)bt * kD;
  float d0 = dec[tid] * W_pgen[tid];
  float d1 = (tid < kD - NT) ? dec[tid + NT] * W_pgen[tid + NT] : 0.f;

  float a0 = 0.f;
  #pragma unroll
  for (int hh = 0; hh < kH; ++hh) {
    const float* ap = attn_w + (((size_t)b * kH + hh) * kT + t) * kS;
    a0 += ap[tid];
  }
  const int key = enc[b * kS + tid];
  const float bias = b_pgen[0];

  const f32x4* x4 = (const f32x4*)(final_output + (size_t)bt * kV);
  f32x4 r[FULL + 1];
  #pragma unroll
  for (int k = 0; k < FULL; ++k) r[k] = x4[tid + k * NT];
  const bool has16 = tid < REM;
  if (has16) r[FULL] = x4[tid + FULL * NT];

  // hash init
  hkey[tid] = -1;        hval[tid] = 0.f;
  hkey[tid + NT] = -1;   hval[tid + NT] = 0.f;

  // ---- Phase A: p_gen partial reduction ----
  {
    float acc = wave_sum(d0 + d1);
    if (lane == 0) redA[wid] = acc;
  }
  __syncthreads();                                   // #1: hash init + redA

  // every thread computes p_gen redundantly (no extra barrier)
  float z = bias;
  #pragma unroll
  for (int w = 0; w < NW; ++w) z += redA[w];
  const float pg = 1.f / (1.f + expf(-z));

  // ---- Phase B: attn mean + softmax over S (kS == NT) ----
  float val;
  {
    a0 *= (1.f / kH);
    float wm = wave_max(a0);
    if (lane == 0) redm[wid] = wm;
    __syncthreads();                                 // #2
    float mx = redm[0];
    #pragma unroll
    for (int w = 1; w < NW; ++w) mx = fmaxf(mx, redm[w]);
    float e0 = __expf(a0 - mx);
    float ws = wave_sum(e0);
    if (lane == 0) reds[wid] = ws;
    __syncthreads();                                 // #3
    float tot = 0.f;
    #pragma unroll
    for (int w = 0; w < NW; ++w) tot += reds[w];
    val = e0 * ((1.f - pg) / tot);
  }

  // ---- Phase C: hash insert (token -> summed copy prob) ----
  {
    unsigned hpos = ((unsigned)key * 2654435761u) >> 22;
    while (true) {
      int prev = atomicCAS(&hkey[hpos], -1, key);
      if (prev == -1 || prev == key) { atomicAdd(&hval[hpos], val); break; }
      hpos = (hpos + 1) & (HASH - 1);
    }
  }

  // ---- Phase D: online softmax over the register-resident row ----
  float m0 = -1e30f, s0 = 0.f, m1 = -1e30f, s1 = 0.f;
  float m2 = -1e30f, s2 = 0.f, m3 = -1e30f, s3 = 0.f;
  #pragma unroll
  for (int k = 0; k + 3 < FULL; k += 4) {            // 0..11
    acc4(m0, s0, r[k]); acc4(m1, s1, r[k + 1]);
    acc4(m2, s2, r[k + 2]); acc4(m3, s3, r[k + 3]);
  }
  acc4(m0, s0, r[12]); acc4(m1, s1, r[13]); acc4(m2, s2, r[14]);
  if (has16) acc4(m3, s3, r[FULL]);
  merge2(m0, s0, m1, s1);
  merge2(m2, s2, m3, s3);
  merge2(m0, s0, m2, s2);
  #pragma unroll
  for (int off = 32; off > 0; off >>= 1) {
    float mb = __shfl_down(m0, off, 64);
    float sb = __shfl_down(s0, off, 64);
    merge2(m0, s0, mb, sb);
  }
  if (lane == 0) { redm2[wid] = m0; reds2[wid] = s0; }
  __syncthreads();                                   // #4: row stats + hash done

  float M = redm2[0], Z = reds2[0];
  #pragma unroll
  for (int w = 1; w < NW; ++w) merge2(M, Z, redm2[w], reds2[w]);
  const float base = logf(pg) - M - logf(Z);

  // ---- Phase E: dense emit straight from registers ----
  f32x4* o4 = (f32x4*)(out + (size_t)bt * kV);
  #pragma unroll
  for (int k = 0; k < FULL; ++k)
    __builtin_nontemporal_store(r[k] + base, &o4[tid + k * NT]);
  if (has16)
    __builtin_nontemporal_store(r[FULL] + base, &o4[tid + FULL * NT]);
  __syncthreads();                                   // #5: dense writes drained

  // ---- Phase F: fixup the <=512 copied tokens ----
  {
    const float* xrow = final_output + (size_t)bt * kV;
    float* orow = out + (size_t)bt * kV;
    const float invZ = 1.f / Z;
    for (int i = tid; i < HASH; i += NT) {
      int k2 = hkey[i];
      if (k2 >= 0) {
        float c = hval[i];
        float x = xrow[k2];
        orow[k2] = logf(pg * expf(x - M) * invZ + c);
      }
    }
  }
}
}  // namespace

extern "C" void kernel_launch(void* const* d_in, const int* in_sizes, int n_in,
                              void* d_out, int out_size, void* d_ws, size_t ws_size,
                              hipStream_t stream) {
  const float* dec = (const float*)d_in[0];
  const float* fin = (const float*)d_in[1];
  const float* aw  = (const float*)d_in[2];
  const float* W   = (const float*)d_in[3];
  const float* bb  = (const float*)d_in[4];
  const int*   enc = (const int*)d_in[5];
  float* out = (float*)d_out;

  pg_fused<<<dim3(kB * kT), dim3(NT), 0, stream>>>(dec, fin, aw, W, bb, enc, out);
}